// Round 3
// baseline (764.700 us; speedup 1.0000x reference)
//
#include <hip/hip_runtime.h>
#include <hip/hip_bf16.h>

#define B_SZ 512
#define U_DIM 1024
#define DU_DIM 512
#define H_DIM 2048
#define Y_DIM 1024
#define K_CAT 1536
#define DELTA_F 0.01f

typedef __hip_bfloat16 bf16;

__device__ __forceinline__ float b2f(bf16 x) { return __bfloat162float(x); }

// Read input element i from a buffer whose dtype is decided at runtime.
// isf32=1 -> float32, isf32=0 -> bfloat16.
__device__ __forceinline__ float ldIn(const void* p, size_t i, int isf32) {
  if (isf32) return ((const float*)p)[i];
  return b2f(((const bf16*)p)[i]);
}

// ---- dtype sniffer: even-indexed uint16s of u~N(0,1) have plausible bf16
// exponent fields iff the buffer is bf16; if f32 they are raw mantissa bits.
__global__ void detect_dtype(const void* __restrict__ u, int* __restrict__ flag) {
  const unsigned short* p = (const unsigned short*)u;
  int lane = threadIdx.x;  // 0..63
  unsigned short v = p[2 * lane];
  int e = (v >> 7) & 0xFF;
  int plausible = (e >= 100 && e <= 140) || (v == 0);
  unsigned long long m = __ballot(plausible);
  if (lane == 0) flag[0] = (__popcll(m) >= 48) ? 0 : 1;  // 0=bf16, 1=f32
}

// ---------------- X = 0.005*(W - W^T), stored bf16 row-major ----------------
__global__ __launch_bounds__(256) void build_X(const void* __restrict__ W, bf16* __restrict__ X,
                                               const int* __restrict__ flagp) {
  const int f32 = *flagp;
  __shared__ float tile[32][33];
  const int bx = blockIdx.x * 32;  // X row block
  const int by = blockIdx.y * 32;  // X col block
  const int tx = threadIdx.x;      // 0..31
  const int ty = threadIdx.y;      // 0..7
#pragma unroll
  for (int r = ty; r < 32; r += 8)
    tile[r][tx] = ldIn(W, (size_t)(by + r) * H_DIM + (bx + tx), f32);
  __syncthreads();
#pragma unroll
  for (int r = ty; r < 32; r += 8) {
    int i = bx + r, j = by + tx;
    float wij = ldIn(W, (size_t)i * H_DIM + j, f32);
    float wji = tile[tx][r];  // W[j][i]
    X[(size_t)i * H_DIM + j] = __float2bfloat16(0.005f * (wij - wji));
  }
}

#define BM 64
#define BN 64
#define BK 16

// ---------------- b = cat(du,u) @ Bw^T   (f32 out) ----------------
__global__ __launch_bounds__(256) void gemm_b(const void* __restrict__ du, const void* __restrict__ u,
                                              const void* __restrict__ Bw, float* __restrict__ b_out,
                                              const int* __restrict__ flagp) {
  const int f32 = *flagp;
  __shared__ float As[BK][BM + 1];
  __shared__ float Bs[BK][BN + 1];
  const int tid = threadIdx.x;
  const int tx = tid & 15, ty = tid >> 4;
  const int row0 = blockIdx.y * BM;
  const int col0 = blockIdx.x * BN;
  float acc[4][4] = {};
  for (int k0 = 0; k0 < K_CAT; k0 += BK) {
#pragma unroll
    for (int s = 0; s < 4; s++) {
      int idx = tid + s * 256;
      int r = idx >> 4, c = idx & 15;
      int gk = k0 + c;
      float av = (gk < DU_DIM) ? ldIn(du, (size_t)(row0 + r) * DU_DIM + gk, f32)
                               : ldIn(u, (size_t)(row0 + r) * U_DIM + (gk - DU_DIM), f32);
      As[c][r] = av;
      Bs[c][r] = ldIn(Bw, (size_t)(col0 + r) * K_CAT + gk, f32);
    }
    __syncthreads();
#pragma unroll
    for (int kk = 0; kk < BK; kk++) {
      float a[4], bb[4];
#pragma unroll
      for (int i = 0; i < 4; i++) a[i] = As[kk][ty + 16 * i];
#pragma unroll
      for (int j = 0; j < 4; j++) bb[j] = Bs[kk][tx + 16 * j];
#pragma unroll
      for (int i = 0; i < 4; i++)
#pragma unroll
        for (int j = 0; j < 4; j++) acc[i][j] += a[i] * bb[j];
    }
    __syncthreads();
  }
#pragma unroll
  for (int i = 0; i < 4; i++) {
    int gr = row0 + ty + 16 * i;
#pragma unroll
    for (int j = 0; j < 4; j++) {
      int gc = col0 + tx + 16 * j;
      b_out[(size_t)gr * H_DIM + gc] = acc[i][j];
    }
  }
}

// ---- hb = DELTA*(b + 0.5*(b @ X^T)); acc[i][j] = sum_k b[i][k]*X[j][k] ----
__global__ __launch_bounds__(256) void gemm_p1(const float* __restrict__ b_in, const bf16* __restrict__ X,
                                               float* __restrict__ hb) {
  __shared__ float As[BK][BM + 1];
  __shared__ float Bs[BK][BN + 1];
  const int tid = threadIdx.x;
  const int tx = tid & 15, ty = tid >> 4;
  const int row0 = blockIdx.y * BM;
  const int col0 = blockIdx.x * BN;
  float acc[4][4] = {};
  for (int k0 = 0; k0 < H_DIM; k0 += BK) {
#pragma unroll
    for (int s = 0; s < 4; s++) {
      int idx = tid + s * 256;
      int r = idx >> 4, c = idx & 15;
      int gk = k0 + c;
      As[c][r] = b_in[(size_t)(row0 + r) * H_DIM + gk];
      Bs[c][r] = b2f(X[(size_t)(col0 + r) * H_DIM + gk]);
    }
    __syncthreads();
#pragma unroll
    for (int kk = 0; kk < BK; kk++) {
      float a[4], bb[4];
#pragma unroll
      for (int i = 0; i < 4; i++) a[i] = As[kk][ty + 16 * i];
#pragma unroll
      for (int j = 0; j < 4; j++) bb[j] = Bs[kk][tx + 16 * j];
#pragma unroll
      for (int i = 0; i < 4; i++)
#pragma unroll
        for (int j = 0; j < 4; j++) acc[i][j] += a[i] * bb[j];
    }
    __syncthreads();
  }
#pragma unroll
  for (int i = 0; i < 4; i++) {
    int gr = row0 + ty + 16 * i;
#pragma unroll
    for (int j = 0; j < 4; j++) {
      int gc = col0 + tx + 16 * j;
      float bv = b_in[(size_t)gr * H_DIM + gc];
      hb[(size_t)gr * H_DIM + gc] = DELTA_F * (bv + 0.5f * acc[i][j]);
    }
  }
}

// ---- y = f32(yrec[j] + hb @ Cw^T) ----
__global__ __launch_bounds__(256) void gemm_y(const float* __restrict__ hb, const void* __restrict__ Cw,
                                              const float* __restrict__ yrec, float* __restrict__ y,
                                              const int* __restrict__ flagp) {
  const int f32 = *flagp;
  __shared__ float As[BK][BM + 1];
  __shared__ float Bs[BK][BN + 1];
  const int tid = threadIdx.x;
  const int tx = tid & 15, ty = tid >> 4;
  const int row0 = blockIdx.y * BM;
  const int col0 = blockIdx.x * BN;
  float acc[4][4] = {};
  for (int k0 = 0; k0 < H_DIM; k0 += BK) {
#pragma unroll
    for (int s = 0; s < 4; s++) {
      int idx = tid + s * 256;
      int r = idx >> 4, c = idx & 15;
      int gk = k0 + c;
      As[c][r] = hb[(size_t)(row0 + r) * H_DIM + gk];
      Bs[c][r] = ldIn(Cw, (size_t)(col0 + r) * H_DIM + gk, f32);
    }
    __syncthreads();
#pragma unroll
    for (int kk = 0; kk < BK; kk++) {
      float a[4], bb[4];
#pragma unroll
      for (int i = 0; i < 4; i++) a[i] = As[kk][ty + 16 * i];
#pragma unroll
      for (int j = 0; j < 4; j++) bb[j] = Bs[kk][tx + 16 * j];
#pragma unroll
      for (int i = 0; i < 4; i++)
#pragma unroll
        for (int j = 0; j < 4; j++) acc[i][j] += a[i] * bb[j];
    }
    __syncthreads();
  }
#pragma unroll
  for (int i = 0; i < 4; i++) {
    int gr = row0 + ty + 16 * i;
#pragma unroll
    for (int j = 0; j < 4; j++) {
      int gc = col0 + tx + 16 * j;
      y[(size_t)gr * Y_DIM + gc] = yrec[gc] + acc[i][j];
    }
  }
}

// ---- out[row] = scale * dot(v, M[row,:]); optionally rec += out.
// M dtype: bf16 if flagp==nullptr (our ws buffer), else per *flagp.
__global__ __launch_bounds__(256) void gemv_rows(const float* __restrict__ v, const void* __restrict__ Mrow,
                                                 int K, float scale, float* __restrict__ out,
                                                 float* __restrict__ rec_acc, const int* __restrict__ flagp) {
  const int f32 = flagp ? *flagp : 0;
  const int lane = threadIdx.x & 63;
  const int wv = threadIdx.x >> 6;
  const int row = blockIdx.x * 4 + wv;
  float s = 0.f;
  for (int k = lane; k < K; k += 64) s += v[k] * ldIn(Mrow, (size_t)row * K + k, f32);
#pragma unroll
  for (int off = 32; off > 0; off >>= 1) s += __shfl_down(s, off);
  if (lane == 0) {
    float r = s * scale;
    out[row] = r;
    if (rec_acc) rec_acc[row] += r;
  }
}

__global__ void init_vecs(const void* __restrict__ h, float* __restrict__ rec, float* __restrict__ hf,
                          const int* __restrict__ flagp) {
  const int f32 = *flagp;
  int i = blockIdx.x * 256 + threadIdx.x;
  float v = ldIn(h, i, f32);
  rec[i] = v;
  hf[i] = v;
}

extern "C" void kernel_launch(void* const* d_in, const int* in_sizes, int n_in,
                              void* d_out, int out_size, void* d_ws, size_t ws_size,
                              hipStream_t stream) {
  const void* u  = d_in[0];
  const void* du = d_in[1];
  const void* W  = d_in[2];
  const void* Bw = d_in[3];
  const void* Cw = d_in[4];
  const void* h  = d_in[5];
  float* y = (float*)d_out;  // OUTPUT IS F32 (round-2 diagnosis: 2.71 == garbled-bf16-as-f32 signature)

  char* w = (char*)d_ws;
  size_t off = 0;
  bf16* X    = (bf16*)(w + off);  off += (size_t)H_DIM * H_DIM * sizeof(bf16);
  float* b   = (float*)(w + off); off += (size_t)B_SZ * H_DIM * sizeof(float);
  float* hb  = (float*)(w + off); off += (size_t)B_SZ * H_DIM * sizeof(float);
  float* rec = (float*)(w + off); off += H_DIM * sizeof(float);
  float* hf  = (float*)(w + off); off += H_DIM * sizeof(float);
  float* q1  = (float*)(w + off); off += H_DIM * sizeof(float);
  float* q2  = (float*)(w + off); off += H_DIM * sizeof(float);
  float* q3  = (float*)(w + off); off += H_DIM * sizeof(float);
  float* yrec= (float*)(w + off); off += Y_DIM * sizeof(float);
  int* dflag = (int*)(w + off);   off += 4 * sizeof(int);
  if (ws_size < off) return;  // workspace too small -> visible failure

  // 0) runtime input-dtype detection (bf16 vs f32)
  detect_dtype<<<1, 64, 0, stream>>>(u, dflag);
  // 1) X = 0.005*(W - W^T)
  build_X<<<dim3(H_DIM / 32, H_DIM / 32), dim3(32, 8), 0, stream>>>(W, X, dflag);
  // 2) b = cat(du,u) @ Bw^T
  gemm_b<<<dim3(H_DIM / BN, B_SZ / BM), 256, 0, stream>>>(du, u, Bw, b, dflag);
  // 3) rec = h*exp(X)^T = h + q1 + q2 + q3 (series; ||X|| ~ 8e-3)
  init_vecs<<<H_DIM / 256, 256, 0, stream>>>(h, rec, hf, dflag);
  gemv_rows<<<H_DIM / 4, 256, 0, stream>>>(hf, X, H_DIM, 1.0f, q1, rec, nullptr);
  gemv_rows<<<H_DIM / 4, 256, 0, stream>>>(q1, X, H_DIM, 0.5f, q2, rec, nullptr);
  gemv_rows<<<H_DIM / 4, 256, 0, stream>>>(q2, X, H_DIM, 1.0f / 3.0f, q3, rec, nullptr);
  // 4) hb = DELTA*(b + 0.5*b@X^T)  (series for b@M^T; next term ~2e-8)
  gemm_p1<<<dim3(H_DIM / BN, B_SZ / BM), 256, 0, stream>>>(b, X, hb);
  // 5) yrec = rec @ Cw^T
  gemv_rows<<<Y_DIM / 4, 256, 0, stream>>>(rec, Cw, H_DIM, 1.0f, yrec, nullptr, dflag);
  // 6) y = yrec + hb @ Cw^T
  gemm_y<<<dim3(Y_DIM / BN, B_SZ / BM), 256, 0, stream>>>(hb, Cw, yrec, y, dflag);
}

// Round 4
// 162.532 us; speedup vs baseline: 4.7049x; 4.7049x over previous
//
#include <hip/hip_runtime.h>
#include <hip/hip_bf16.h>

// Evidence from rounds 0-3: inputs are f32 (round-0 NaN when read as bf16),
// output is f32 (round-2 absmax 2.71 == bf16-written-to-f32-buffer signature;
// round 3 passed with f32 out, absmax 7.8e-3 = 1 bf16 ulp at max).

#define B_SZ 512
#define U_DIM 1024
#define DU_DIM 512
#define H_DIM 2048
#define Y_DIM 1024
#define K_CAT 1536
#define DELTA_F 0.01f

typedef __hip_bfloat16 bf16;

using bf16x8f = __attribute__((ext_vector_type(8))) short;
using f32x4   = __attribute__((ext_vector_type(4))) float;

__device__ __forceinline__ short f2bs(float x) {
  union { bf16 b; short s; } u; u.b = __float2bfloat16(x); return u.s;
}
__device__ __forceinline__ float blo(unsigned v) { return __uint_as_float(v << 16); }
__device__ __forceinline__ float bhi(unsigned v) { return __uint_as_float(v & 0xffff0000u); }

// ---------------- X = 0.005*(W - W^T), bf16 row-major (round-3 verified) ----------------
__global__ __launch_bounds__(256) void build_X(const float* __restrict__ W, bf16* __restrict__ X) {
  __shared__ float tile[32][33];
  const int bx = blockIdx.x * 32, by = blockIdx.y * 32;
  const int tx = threadIdx.x, ty = threadIdx.y;
#pragma unroll
  for (int r = ty; r < 32; r += 8)
    tile[r][tx] = W[(size_t)(by + r) * H_DIM + (bx + tx)];
  __syncthreads();
#pragma unroll
  for (int r = ty; r < 32; r += 8) {
    int i = bx + r, j = by + tx;
    float wij = W[(size_t)i * H_DIM + j];
    float wji = tile[tx][r];
    X[(size_t)i * H_DIM + j] = __float2bfloat16(0.005f * (wij - wji));
  }
}

// ---------------- convert z=cat(du,u), Bw, Cw to bf16 (one grid-stride pass) ----------------
__global__ __launch_bounds__(256) void convert_all(const float* __restrict__ du, const float* __restrict__ u,
                                                   const float* __restrict__ Bw, const float* __restrict__ Cw,
                                                   short* __restrict__ z, short* __restrict__ Bwb,
                                                   short* __restrict__ Cwb) {
  const int nz = B_SZ * K_CAT / 4;       // 196608
  const int nb = H_DIM * K_CAT / 4;      // 786432
  const int nc = Y_DIM * H_DIM / 4;      // 524288
  for (int i = blockIdx.x * 256 + threadIdx.x; i < nz + nb + nc; i += gridDim.x * 256) {
    float4 v; short* dst;
    if (i < nz) {
      int e = i * 4; int row = e / K_CAT, col = e % K_CAT;
      const float* src = (col < DU_DIM) ? du + (size_t)row * DU_DIM + col
                                        : u + (size_t)row * U_DIM + (col - DU_DIM);
      v = *(const float4*)src; dst = z + e;
    } else if (i < nz + nb) {
      v = ((const float4*)Bw)[i - nz]; dst = Bwb + (size_t)(i - nz) * 4;
    } else {
      v = ((const float4*)Cw)[i - nz - nb]; dst = Cwb + (size_t)(i - nz - nb) * 4;
    }
    short4 o; o.x = f2bs(v.x); o.y = f2bs(v.y); o.z = f2bs(v.z); o.w = f2bs(v.w);
    *(short4*)dst = o;
  }
}

// ---------------- rec[row] = h[row] + sum_k X[row][k]*h[k]  (series to X^1) ----------------
__global__ __launch_bounds__(256) void gemv_rec(const short* __restrict__ X, const float* __restrict__ h,
                                                float* __restrict__ rec) {
  const int lane = threadIdx.x & 63, wave = threadIdx.x >> 6;
  const int row = blockIdx.x * 4 + wave;
  const short* xr = X + (size_t)row * H_DIM;
  float s = 0.f;
#pragma unroll
  for (int it = 0; it < 4; it++) {
    int k = it * 512 + lane * 8;
    int4 px = *(const int4*)(xr + k);
    float4 h0 = *(const float4*)(h + k);
    float4 h1 = *(const float4*)(h + k + 4);
    unsigned a = (unsigned)px.x, b = (unsigned)px.y, c = (unsigned)px.z, d = (unsigned)px.w;
    s += blo(a) * h0.x + bhi(a) * h0.y + blo(b) * h0.z + bhi(b) * h0.w;
    s += blo(c) * h1.x + bhi(c) * h1.y + blo(d) * h1.z + bhi(d) * h1.w;
  }
#pragma unroll
  for (int off = 32; off > 0; off >>= 1) s += __shfl_down(s, off);
  if (lane == 0) rec[row] = h[row] + s;
}

// ---------------- yrec[row] = dot(rec, Cw[row,:])  (f32 Cw for accuracy) ----------------
__global__ __launch_bounds__(256) void gemv_yrec(const float* __restrict__ Cw, const float* __restrict__ rec,
                                                 float* __restrict__ yrec) {
  const int lane = threadIdx.x & 63, wave = threadIdx.x >> 6;
  const int row = blockIdx.x * 4 + wave;
  const float* cr = Cw + (size_t)row * H_DIM;
  float s = 0.f;
#pragma unroll
  for (int it = 0; it < 8; it++) {
    int k = it * 256 + lane * 4;
    float4 c = *(const float4*)(cr + k);
    float4 r = *(const float4*)(rec + k);
    s += c.x * r.x + c.y * r.y + c.z * r.z + c.w * r.w;
  }
#pragma unroll
  for (int off = 32; off > 0; off >>= 1) s += __shfl_down(s, off);
  if (lane == 0) yrec[row] = s;
}

// ---------------- MFMA bf16 GEMM: C[M][N] = A[M][K] @ B[N][K]^T ----------------
// 128x128 tile, BK=32, 256 threads (4 waves as 2x2 of 64x64), LDS double-buffer
// with register prefetch. EPI=0: store bf16. EPI=1: out f32 = bias[col]+scale*acc.
#define TM 128
#define TN 128
#define TKB 32

template <int KDIM, int EPI>
__global__ __launch_bounds__(256) void mfma_gemm(const short* __restrict__ A, const short* __restrict__ B,
                                                 const float* __restrict__ bias, float scale,
                                                 void* __restrict__ out, int Ncols) {
  __shared__ __align__(16) short As[2][TM * TKB];
  __shared__ __align__(16) short Bs[2][TN * TKB];
  const int tid = threadIdx.x;
  const int lane = tid & 63, wave = tid >> 6;
  const int wm = wave >> 1, wn = wave & 1;
  const int row0 = blockIdx.y * TM, col0 = blockIdx.x * TN;
  // staging: granule g (16B) -> row=g>>2, kchunk=g&3; thread t handles g=t and g=t+256
  const int r_a = tid >> 2, c_a = tid & 3;
  f32x4 acc[4][4] = {};
  int4 ra0, ra1, rb0, rb1;
  {
    const short* Ap = A + (size_t)(row0 + r_a) * KDIM + c_a * 8;
    const short* Bp = B + (size_t)(col0 + r_a) * KDIM + c_a * 8;
    ra0 = *(const int4*)Ap;  ra1 = *(const int4*)(Ap + (size_t)64 * KDIM);
    rb0 = *(const int4*)Bp;  rb1 = *(const int4*)(Bp + (size_t)64 * KDIM);
  }
  *(int4*)&As[0][tid * 8] = ra0;  *(int4*)&As[0][tid * 8 + 2048] = ra1;
  *(int4*)&Bs[0][tid * 8] = rb0;  *(int4*)&Bs[0][tid * 8 + 2048] = rb1;
  const int NT = KDIM / TKB;
  const int kq = (lane >> 4) * 8;   // quad*8 : k-offset of this lane's fragment
  const int rm = lane & 15;         // row/col within 16-tile
  for (int kt = 0; kt < NT; kt++) {
    const int cur = kt & 1;
    if (kt + 1 < NT) {  // prefetch next tile into registers (latency overlapped w/ MFMA)
      const short* Ap = A + (size_t)(row0 + r_a) * KDIM + (kt + 1) * TKB + c_a * 8;
      const short* Bp = B + (size_t)(col0 + r_a) * KDIM + (kt + 1) * TKB + c_a * 8;
      ra0 = *(const int4*)Ap;  ra1 = *(const int4*)(Ap + (size_t)64 * KDIM);
      rb0 = *(const int4*)Bp;  rb1 = *(const int4*)(Bp + (size_t)64 * KDIM);
    }
    __syncthreads();  // prev writes to [cur] visible; everyone done with [cur^1]
    bf16x8f af[4], bf[4];
#pragma unroll
    for (int i = 0; i < 4; i++) {
      af[i] = *(const bf16x8f*)&As[cur][(wm * 64 + 16 * i + rm) * TKB + kq];
      bf[i] = *(const bf16x8f*)&Bs[cur][(wn * 64 + 16 * i + rm) * TKB + kq];
    }
#pragma unroll
    for (int i = 0; i < 4; i++)
#pragma unroll
      for (int j = 0; j < 4; j++)
        acc[i][j] = __builtin_amdgcn_mfma_f32_16x16x32_bf16(af[i], bf[j], acc[i][j], 0, 0, 0);
    if (kt + 1 < NT) {
      const int nxt = cur ^ 1;
      *(int4*)&As[nxt][tid * 8] = ra0;  *(int4*)&As[nxt][tid * 8 + 2048] = ra1;
      *(int4*)&Bs[nxt][tid * 8] = rb0;  *(int4*)&Bs[nxt][tid * 8 + 2048] = rb1;
    }
  }
  // epilogue: C/D layout col=lane&15, row=(lane>>4)*4+reg  [m89 verified]
  const int regrow = (lane >> 4) * 4;
#pragma unroll
  for (int i = 0; i < 4; i++) {
#pragma unroll
    for (int j = 0; j < 4; j++) {
      int gc = col0 + wn * 64 + 16 * j + rm;
#pragma unroll
      for (int r = 0; r < 4; r++) {
        int gr = row0 + wm * 64 + 16 * i + regrow + r;
        float v = acc[i][j][r];
        if (EPI == 0) ((short*)out)[(size_t)gr * Ncols + gc] = f2bs(v);
        else          ((float*)out)[(size_t)gr * Ncols + gc] = bias[gc] + scale * v;
      }
    }
  }
}

extern "C" void kernel_launch(void* const* d_in, const int* in_sizes, int n_in,
                              void* d_out, int out_size, void* d_ws, size_t ws_size,
                              hipStream_t stream) {
  const float* u  = (const float*)d_in[0];
  const float* du = (const float*)d_in[1];
  const float* W  = (const float*)d_in[2];
  const float* Bw = (const float*)d_in[3];
  const float* Cw = (const float*)d_in[4];
  const float* h  = (const float*)d_in[5];
  float* y = (float*)d_out;

  char* w = (char*)d_ws;
  size_t off = 0;
  bf16* X    = (bf16*)(w + off);  off += (size_t)H_DIM * H_DIM * sizeof(bf16);   // 8 MB
  short* z   = (short*)(w + off); off += (size_t)B_SZ * K_CAT * sizeof(short);   // 1.5 MB
  short* Bwb = (short*)(w + off); off += (size_t)H_DIM * K_CAT * sizeof(short);  // 6 MB
  short* Cwb = (short*)(w + off); off += (size_t)Y_DIM * H_DIM * sizeof(short);  // 4 MB
  short* bb  = (short*)(w + off); off += (size_t)B_SZ * H_DIM * sizeof(short);   // 2 MB
  float* rec = (float*)(w + off); off += H_DIM * sizeof(float);
  float* yrec= (float*)(w + off); off += Y_DIM * sizeof(float);
  if (ws_size < off) return;

  // 1) X = 0.005*(W - W^T)   (only consumer: gemv_rec; series terms X^2+ dropped, err <4e-5)
  build_X<<<dim3(H_DIM / 32, H_DIM / 32), dim3(32, 8), 0, stream>>>(W, X);
  // 2) bf16 conversions for MFMA operands
  convert_all<<<1024, 256, 0, stream>>>(du, u, Bw, Cw, z, Bwb, Cwb);
  // 3) b = cat(du,u) @ Bw^T  -> bf16  (M=512,N=2048,K=1536)
  mfma_gemm<K_CAT, 0><<<dim3(H_DIM / TN, B_SZ / TM), 256, 0, stream>>>(z, Bwb, nullptr, 0.f, bb, H_DIM);
  // 4) rec = h + X@h
  gemv_rec<<<H_DIM / 4, 256, 0, stream>>>((const short*)X, h, rec);
  // 5) yrec = rec @ Cw^T  (f32 Cw: keeps dominant term exact)
  gemv_yrec<<<Y_DIM / 4, 256, 0, stream>>>(Cw, rec, yrec);
  // 6) y = yrec[col] + DELTA * (b @ Cw^T)   (M=512,N=1024,K=2048)
  mfma_gemm<H_DIM, 1><<<dim3(Y_DIM / TN, B_SZ / TM), 256, 0, stream>>>(bb, Cwb, yrec, DELTA_F, y, Y_DIM);
}

// Round 5
// 140.444 us; speedup vs baseline: 5.4449x; 1.1573x over previous
//
#include <hip/hip_runtime.h>
#include <hip/hip_bf16.h>

// Established: inputs f32, output f32 (rounds 0-3). absmax floor 7.8e-3 = 1 bf16 ulp.
// Math: y = Cw@(h + X@h) + DELTA*(cat(du,u)@Bw^T)@Cw^T, X = 0.005*(W - W^T);
// higher series terms (X^2/2 etc.) contribute <4e-5 to y -> dropped (validated r3/r4).

#define B_SZ 512
#define U_DIM 1024
#define DU_DIM 512
#define H_DIM 2048
#define Y_DIM 1024
#define K_CAT 1536
#define DELTA_F 0.01f

typedef __hip_bfloat16 bf16;
using bf16x8f = __attribute__((ext_vector_type(8))) short;
using f32x4   = __attribute__((ext_vector_type(4))) float;

__device__ __forceinline__ short f2bs(float x) {
  union { bf16 b; short s; } u; u.b = __float2bfloat16(x); return u.s;
}

// pack 8 f32 -> 8 bf16 (int4)
__device__ __forceinline__ int4 pack8(const float4 v0, const float4 v1) {
  union { short s[8]; int4 i; } o;
  o.s[0] = f2bs(v0.x); o.s[1] = f2bs(v0.y); o.s[2] = f2bs(v0.z); o.s[3] = f2bs(v0.w);
  o.s[4] = f2bs(v1.x); o.s[5] = f2bs(v1.y); o.s[6] = f2bs(v1.z); o.s[7] = f2bs(v1.w);
  return o.i;
}

// ---------------- wh = W@h  (blocks 0..511) and wth += W^T@h (blocks 512..767) ----------------
__global__ __launch_bounds__(256) void gemv_wh_wth(const float* __restrict__ W, const float* __restrict__ h,
                                                   float* __restrict__ wh, float* __restrict__ wth) {
  const int b = blockIdx.x;
  if (b < 512) {  // row dots: wh[row] = dot(W[row,:], h)
    const int lane = threadIdx.x & 63, wave = threadIdx.x >> 6;
    const int row = b * 4 + wave;
    const float* wr = W + (size_t)row * H_DIM;
    float s = 0.f;
#pragma unroll
    for (int it = 0; it < 8; it++) {
      int k = it * 256 + lane * 4;
      float4 a = *(const float4*)(wr + k);
      float4 hv = *(const float4*)(h + k);
      s += a.x * hv.x + a.y * hv.y + a.z * hv.z + a.w * hv.w;
    }
#pragma unroll
    for (int off = 32; off > 0; off >>= 1) s += __shfl_down(s, off);
    if (lane == 0) wh[row] = s;
  } else {  // column partials: wth[k] += sum_{i in chunk} W[i][k]*h[i]
    const int e = b - 512;          // 0..255
    const int colg = e & 7;         // 8 col groups of 256
    const int rowg = e >> 3;        // 32 row chunks of 64
    const int k = colg * 256 + threadIdx.x;
    float s = 0.f;
    const float* base = W + (size_t)rowg * 64 * H_DIM + k;
#pragma unroll 8
    for (int i = 0; i < 64; i++) s += base[(size_t)i * H_DIM] * h[rowg * 64 + i];
    atomicAdd(&wth[k], s);
  }
}

// ---------------- yrec[row] = dot(Cw[row,:], h + 0.005*(wh - wth)) ----------------
__global__ __launch_bounds__(256) void gemv_yrec(const float* __restrict__ Cw, const float* __restrict__ h,
                                                 const float* __restrict__ wh, const float* __restrict__ wth,
                                                 float* __restrict__ yrec) {
  const int lane = threadIdx.x & 63, wave = threadIdx.x >> 6;
  const int row = blockIdx.x * 4 + wave;
  const float* cr = Cw + (size_t)row * H_DIM;
  float s = 0.f;
#pragma unroll
  for (int it = 0; it < 8; it++) {
    int k = it * 256 + lane * 4;
    float4 c = *(const float4*)(cr + k);
    float4 hv = *(const float4*)(h + k);
    float4 a = *(const float4*)(wh + k);
    float4 bq = *(const float4*)(wth + k);
    s += c.x * (hv.x + 0.005f * (a.x - bq.x));
    s += c.y * (hv.y + 0.005f * (a.y - bq.y));
    s += c.z * (hv.z + 0.005f * (a.z - bq.z));
    s += c.w * (hv.w + 0.005f * (a.w - bq.w));
  }
#pragma unroll
  for (int off = 32; off > 0; off >>= 1) s += __shfl_down(s, off);
  if (lane == 0) yrec[row] = s;
}

// ---------------- MFMA bf16 GEMM, 64x64 tile, BK=64, inline f32->bf16 staging --------------
// C[M][N] = A[M][K] @ B[N][K]^T.  AMODE: 0 = A bf16 plain, 2 = A f32 concat(du|u).
// B always f32 (converted inline).  EPI: 0 = store bf16; 1 = f32 bias[col]+scale*acc.
#define TKB 64
#define LDP 72  // padded row stride in shorts (144B -> 2-way LDS banking, free)

template <int KDIM, int AMODE, int EPI>
__global__ __launch_bounds__(256) void mfma_gemm(const void* __restrict__ A, const float* __restrict__ A2,
                                                 const float* __restrict__ B, const float* __restrict__ bias,
                                                 float scale, void* __restrict__ out, int Ncols) {
  __shared__ __align__(16) short As[2][64 * LDP];
  __shared__ __align__(16) short Bs[2][64 * LDP];
  const int tid = threadIdx.x;
  const int lane = tid & 63, wave = tid >> 6;
  const int wm = wave >> 1, wn = wave & 1;
  const int row0 = blockIdx.y * 64, col0 = blockIdx.x * 64;
  // granule: 8 shorts. 512 granules per matrix; thread t -> g=t and g=t+256.
  const int r1 = tid >> 3, kc1 = tid & 7;           // granule 1: rows 0..31
  const int r2 = r1 + 32, kc2 = kc1;                // granule 2: rows 32..63
  f32x4 acc[2][2] = {};

  int4 pa1, pa2, pb1, pb2;
  auto loadA = [&](int row, int kc, int kt) -> int4 {
    int col = kt * TKB + kc * 8;
    if (AMODE == 0) {
      return *(const int4*)((const short*)A + (size_t)(row0 + row) * KDIM + col);
    } else {
      const float* p = (col < DU_DIM) ? A2 + (size_t)(row0 + row) * DU_DIM + col
                                      : (const float*)A + (size_t)(row0 + row) * U_DIM + (col - DU_DIM);
      return pack8(*(const float4*)p, *(const float4*)(p + 4));
    }
  };
  auto loadB = [&](int row, int kc, int kt) -> int4 {
    const float* p = B + (size_t)(col0 + row) * KDIM + kt * TKB + kc * 8;
    return pack8(*(const float4*)p, *(const float4*)(p + 4));
  };

  pa1 = loadA(r1, kc1, 0); pa2 = loadA(r2, kc2, 0);
  pb1 = loadB(r1, kc1, 0); pb2 = loadB(r2, kc2, 0);
  *(int4*)&As[0][r1 * LDP + kc1 * 8] = pa1;  *(int4*)&As[0][r2 * LDP + kc2 * 8] = pa2;
  *(int4*)&Bs[0][r1 * LDP + kc1 * 8] = pb1;  *(int4*)&Bs[0][r2 * LDP + kc2 * 8] = pb2;

  const int NT = KDIM / TKB;
  const int kq = (lane >> 4) * 8;  // lane's k-offset within a 32-k step
  const int rm = lane & 15;
  for (int kt = 0; kt < NT; kt++) {
    const int cur = kt & 1;
    if (kt + 1 < NT) {
      pa1 = loadA(r1, kc1, kt + 1); pa2 = loadA(r2, kc2, kt + 1);
      pb1 = loadB(r1, kc1, kt + 1); pb2 = loadB(r2, kc2, kt + 1);
    }
    __syncthreads();
    bf16x8f af[2][2], bf[2][2];
#pragma unroll
    for (int ks = 0; ks < 2; ks++)
#pragma unroll
      for (int i = 0; i < 2; i++) {
        af[ks][i] = *(const bf16x8f*)&As[cur][(wm * 32 + 16 * i + rm) * LDP + ks * 32 + kq];
        bf[ks][i] = *(const bf16x8f*)&Bs[cur][(wn * 32 + 16 * i + rm) * LDP + ks * 32 + kq];
      }
#pragma unroll
    for (int ks = 0; ks < 2; ks++)
#pragma unroll
      for (int i = 0; i < 2; i++)
#pragma unroll
        for (int j = 0; j < 2; j++)
          acc[i][j] = __builtin_amdgcn_mfma_f32_16x16x32_bf16(af[ks][i], bf[ks][j], acc[i][j], 0, 0, 0);
    if (kt + 1 < NT) {
      const int nxt = cur ^ 1;
      *(int4*)&As[nxt][r1 * LDP + kc1 * 8] = pa1;  *(int4*)&As[nxt][r2 * LDP + kc2 * 8] = pa2;
      *(int4*)&Bs[nxt][r1 * LDP + kc1 * 8] = pb1;  *(int4*)&Bs[nxt][r2 * LDP + kc2 * 8] = pb2;
      __syncthreads();
    }
  }
  // C/D layout: col = lane&15, row = (lane>>4)*4 + reg  [verified r4]
  const int regrow = (lane >> 4) * 4;
#pragma unroll
  for (int i = 0; i < 2; i++)
#pragma unroll
    for (int j = 0; j < 2; j++) {
      int gc = col0 + wn * 32 + 16 * j + rm;
#pragma unroll
      for (int r = 0; r < 4; r++) {
        int gr = row0 + wm * 32 + 16 * i + regrow + r;
        float v = acc[i][j][r];
        if (EPI == 0) ((short*)out)[(size_t)gr * Ncols + gc] = f2bs(v);
        else          ((float*)out)[(size_t)gr * Ncols + gc] = bias[gc] + scale * v;
      }
    }
}

extern "C" void kernel_launch(void* const* d_in, const int* in_sizes, int n_in,
                              void* d_out, int out_size, void* d_ws, size_t ws_size,
                              hipStream_t stream) {
  const float* u  = (const float*)d_in[0];
  const float* du = (const float*)d_in[1];
  const float* W  = (const float*)d_in[2];
  const float* Bw = (const float*)d_in[3];
  const float* Cw = (const float*)d_in[4];
  const float* h  = (const float*)d_in[5];
  float* y = (float*)d_out;

  char* w = (char*)d_ws;
  size_t off = 0;
  short* bb  = (short*)(w + off); off += (size_t)B_SZ * H_DIM * sizeof(short);  // 2 MB
  float* wh  = (float*)(w + off); off += H_DIM * sizeof(float);
  float* wth = (float*)(w + off); off += H_DIM * sizeof(float);
  float* yrec= (float*)(w + off); off += Y_DIM * sizeof(float);
  if (ws_size < off) return;

  // wth is atomic-accumulated -> must start at 0 (ws is poisoned 0xAA)
  hipMemsetAsync(wth, 0, H_DIM * sizeof(float), stream);
  // wh = W@h ; wth = W^T@h   (one kernel, 768 blocks)
  gemv_wh_wth<<<768, 256, 0, stream>>>(W, h, wh, wth);
  // yrec = Cw @ (h + 0.005*(wh - wth))
  gemv_yrec<<<Y_DIM / 4, 256, 0, stream>>>(Cw, h, wh, wth, yrec);
  // bb = bf16( cat(du,u) @ Bw^T )    M=512,N=2048,K=1536 -> 256 blocks
  mfma_gemm<K_CAT, 2, 0><<<dim3(H_DIM / 64, B_SZ / 64), 256, 0, stream>>>(
      u, du, Bw, nullptr, 0.f, bb, H_DIM);
  // y = yrec[col] + DELTA*(bb @ Cw^T)  M=512,N=1024,K=2048 -> 128 blocks
  mfma_gemm<H_DIM, 0, 1><<<dim3(Y_DIM / 64, B_SZ / 64), 256, 0, stream>>>(
      bb, nullptr, Cw, yrec, DELTA_F, y, Y_DIM);
}

// Round 6
// 123.406 us; speedup vs baseline: 6.1966x; 1.1381x over previous
//
#include <hip/hip_runtime.h>
#include <hip/hip_bf16.h>

// Established: inputs f32, output f32. absmax floor 7.8e-3 = 1 bf16 ulp (r3-r5).
// Math: y = Cw@(h + 0.005*(W@h - W^T@h)) + DELTA*(cat(du,u)@Bw^T)@Cw^T
// (series terms X^2+ contribute <4e-5 -> dropped; validated r3-r5).
// Harness floor ~60us/iter (ws poison + input restore) -- optimize the rest.

#define B_SZ 512
#define U_DIM 1024
#define DU_DIM 512
#define H_DIM 2048
#define Y_DIM 1024
#define K_CAT 1536
#define DELTA_F 0.01f

typedef __hip_bfloat16 bf16;
using bf16x8f = __attribute__((ext_vector_type(8))) short;
using f32x4   = __attribute__((ext_vector_type(4))) float;

__device__ __forceinline__ short f2bs(float x) {
  union { bf16 b; short s; } u; u.b = __float2bfloat16(x); return u.s;
}
__device__ __forceinline__ int4 pack8(const float4 v0, const float4 v1) {
  union { short s[8]; int4 i; } o;
  o.s[0] = f2bs(v0.x); o.s[1] = f2bs(v0.y); o.s[2] = f2bs(v0.z); o.s[3] = f2bs(v0.w);
  o.s[4] = f2bs(v1.x); o.s[5] = f2bs(v1.y); o.s[6] = f2bs(v1.z); o.s[7] = f2bs(v1.w);
  return o.i;
}

// ---------------- shared MFMA GEMM tile: C[32 x 64] = A[32xK] @ B[64xK]^T -----------
// 256 threads = 4 waves in 2x2; wave computes 16 rows x 32 cols. BK=64, LDS dbuf +
// register prefetch (structure verified r4/r5). LDP=72 shorts (144B stride -> 2-way
// LDS banking, free per m136).
#define LDP 72
#define LDS_SHORTS (2 * 32 * LDP + 2 * 64 * LDP)

template <int KDIM, int EPI>
__device__ __forceinline__ void gemm_tile(short* lds, const short* __restrict__ A,
                                          const short* __restrict__ B, const float* __restrict__ bias,
                                          float scale, void* __restrict__ out, int Ncols,
                                          int mt, int nt) {
  short* As0 = lds;                   // [2][32*LDP]
  short* Bs0 = lds + 2 * 32 * LDP;    // [2][64*LDP]
  const int tid = threadIdx.x;
  const int lane = tid & 63, wave = tid >> 6;
  const int wm = wave >> 1, wn = wave & 1;
  const int row0 = mt * 32, col0 = nt * 64;
  const int rA = tid >> 3, kc = (tid & 7) * 8;  // A granule row 0..31; B rows rA, rA+32
  f32x4 acc[2] = {};
  int4 pa, pb1, pb2;
  auto ldA  = [&](int kt) { return *(const int4*)(A + (size_t)(row0 + rA) * KDIM + kt * 64 + kc); };
  auto ldB1 = [&](int kt) { return *(const int4*)(B + (size_t)(col0 + rA) * KDIM + kt * 64 + kc); };
  auto ldB2 = [&](int kt) { return *(const int4*)(B + (size_t)(col0 + rA + 32) * KDIM + kt * 64 + kc); };
  pa = ldA(0); pb1 = ldB1(0); pb2 = ldB2(0);
  *(int4*)&As0[rA * LDP + kc] = pa;
  *(int4*)&Bs0[rA * LDP + kc] = pb1;
  *(int4*)&Bs0[(rA + 32) * LDP + kc] = pb2;
  const int NT = KDIM / 64;
  const int kq = (lane >> 4) * 8, rm = lane & 15;
  for (int kt = 0; kt < NT; kt++) {
    const int cur = kt & 1;
    if (kt + 1 < NT) { pa = ldA(kt + 1); pb1 = ldB1(kt + 1); pb2 = ldB2(kt + 1); }
    __syncthreads();
    const short* Ac = As0 + cur * (32 * LDP);
    const short* Bc = Bs0 + cur * (64 * LDP);
    bf16x8f af[2], bfr[2][2];
#pragma unroll
    for (int ks = 0; ks < 2; ks++) {
      af[ks] = *(const bf16x8f*)&Ac[(wm * 16 + rm) * LDP + ks * 32 + kq];
#pragma unroll
      for (int j = 0; j < 2; j++)
        bfr[ks][j] = *(const bf16x8f*)&Bc[(wn * 32 + 16 * j + rm) * LDP + ks * 32 + kq];
    }
#pragma unroll
    for (int ks = 0; ks < 2; ks++)
#pragma unroll
      for (int j = 0; j < 2; j++)
        acc[j] = __builtin_amdgcn_mfma_f32_16x16x32_bf16(af[ks], bfr[ks][j], acc[j], 0, 0, 0);
    if (kt + 1 < NT) {
      short* An = As0 + (cur ^ 1) * (32 * LDP);
      short* Bn = Bs0 + (cur ^ 1) * (64 * LDP);
      *(int4*)&An[rA * LDP + kc] = pa;
      *(int4*)&Bn[rA * LDP + kc] = pb1;
      *(int4*)&Bn[(rA + 32) * LDP + kc] = pb2;
      __syncthreads();
    }
  }
  // C/D: col = lane&15, row = (lane>>4)*4 + reg  [verified r4/r5]
  const int quad = lane >> 4;
#pragma unroll
  for (int j = 0; j < 2; j++) {
    int gc = col0 + wn * 32 + 16 * j + rm;
#pragma unroll
    for (int r = 0; r < 4; r++) {
      int gr = row0 + wm * 16 + quad * 4 + r;
      float v = acc[j][r];
      if (EPI == 0) ((short*)out)[(size_t)gr * Ncols + gc] = f2bs(v);
      else          ((float*)out)[(size_t)gr * Ncols + gc] = bias[gc] + scale * v;
    }
  }
}

// ---------------- K1: wh = W@h (blk 0..511), wth += W^T@h (512..767), ----------------
// ----------------     convert z|Bw|Cw -> bf16 (768..1279, grid-stride)  ----------------
#define NZ (B_SZ * K_CAT / 8)
#define NB (H_DIM * K_CAT / 8)
#define NC (Y_DIM * H_DIM / 8)

__global__ __launch_bounds__(256) void k1(const float* __restrict__ W, const float* __restrict__ h,
                                          const float* __restrict__ du, const float* __restrict__ u,
                                          const float* __restrict__ Bw, const float* __restrict__ Cw,
                                          float* __restrict__ wh, float* __restrict__ wth,
                                          short* __restrict__ z, short* __restrict__ Bwb,
                                          short* __restrict__ Cwb) {
  const int b = blockIdx.x;
  if (b < 512) {  // wh[row] = dot(W[row,:], h)
    const int lane = threadIdx.x & 63, wave = threadIdx.x >> 6;
    const int row = b * 4 + wave;
    const float* wr = W + (size_t)row * H_DIM;
    float s = 0.f;
#pragma unroll
    for (int it = 0; it < 8; it++) {
      int k = it * 256 + lane * 4;
      float4 a = *(const float4*)(wr + k);
      float4 hv = *(const float4*)(h + k);
      s += a.x * hv.x + a.y * hv.y + a.z * hv.z + a.w * hv.w;
    }
#pragma unroll
    for (int off = 32; off > 0; off >>= 1) s += __shfl_down(s, off);
    if (lane == 0) wh[row] = s;
  } else if (b < 768) {  // wth[k] += partial column dot
    const int e = b - 512;
    const int colg = e & 7, rowg = e >> 3;
    const int k = colg * 256 + threadIdx.x;
    float s = 0.f;
    const float* base = W + (size_t)rowg * 64 * H_DIM + k;
#pragma unroll 8
    for (int i = 0; i < 64; i++) s += base[(size_t)i * H_DIM] * h[rowg * 64 + i];
    atomicAdd(&wth[k], s);
  } else {  // bf16 conversions
    const int NG = NZ + NB + NC;
    for (int g = (b - 768) * 256 + threadIdx.x; g < NG; g += 512 * 256) {
      const float* src; short* dst;
      if (g < NZ) {
        int e = g * 8, row = e / K_CAT, col = e % K_CAT;
        src = (col < DU_DIM) ? du + (size_t)row * DU_DIM + col
                             : u + (size_t)row * U_DIM + (col - DU_DIM);
        dst = z + e;
      } else if (g < NZ + NB) {
        int e = (g - NZ) * 8; src = Bw + e; dst = Bwb + e;
      } else {
        int e = (g - NZ - NB) * 8; src = Cw + e; dst = Cwb + e;
      }
      *(int4*)dst = pack8(*(const float4*)src, *(const float4*)(src + 4));
    }
  }
}

// ---------------- K2: gemm_b tiles (blk 0..511) + yrec gemv (512..767) ----------------
__global__ __launch_bounds__(256) void k2(const short* __restrict__ z, const short* __restrict__ Bwb,
                                          short* __restrict__ bb, const float* __restrict__ Cw,
                                          const float* __restrict__ h, const float* __restrict__ wh,
                                          const float* __restrict__ wth, float* __restrict__ yrec) {
  __shared__ __align__(16) short lds[LDS_SHORTS];
  const int b = blockIdx.x;
  if (b < 512) {  // bb = bf16(z @ Bwb^T): M=512 (16 mt), N=2048 (32 nt)
    gemm_tile<K_CAT, 0>(lds, z, Bwb, nullptr, 0.f, bb, H_DIM, b >> 5, b & 31);
  } else {  // yrec[row] = dot(Cw[row,:], h + 0.005*(wh - wth))  (f32 Cw for accuracy)
    const int lane = threadIdx.x & 63, wave = threadIdx.x >> 6;
    const int row = (b - 512) * 4 + wave;
    const float* cr = Cw + (size_t)row * H_DIM;
    float s = 0.f;
#pragma unroll
    for (int it = 0; it < 8; it++) {
      int k = it * 256 + lane * 4;
      float4 c = *(const float4*)(cr + k);
      float4 hv = *(const float4*)(h + k);
      float4 a = *(const float4*)(wh + k);
      float4 bq = *(const float4*)(wth + k);
      s += c.x * (hv.x + 0.005f * (a.x - bq.x));
      s += c.y * (hv.y + 0.005f * (a.y - bq.y));
      s += c.z * (hv.z + 0.005f * (a.z - bq.z));
      s += c.w * (hv.w + 0.005f * (a.w - bq.w));
    }
#pragma unroll
    for (int off = 32; off > 0; off >>= 1) s += __shfl_down(s, off);
    if (lane == 0) yrec[row] = s;
  }
}

// ---------------- K3: y = yrec[col] + DELTA*(bb @ Cwb^T): M=512 (16 mt), N=1024 (16 nt) ----
__global__ __launch_bounds__(256) void k3(const short* __restrict__ bb, const short* __restrict__ Cwb,
                                          const float* __restrict__ yrec, float* __restrict__ y) {
  __shared__ __align__(16) short lds[LDS_SHORTS];
  gemm_tile<H_DIM, 1>(lds, bb, Cwb, yrec, DELTA_F, y, Y_DIM, blockIdx.x >> 4, blockIdx.x & 15);
}

extern "C" void kernel_launch(void* const* d_in, const int* in_sizes, int n_in,
                              void* d_out, int out_size, void* d_ws, size_t ws_size,
                              hipStream_t stream) {
  const float* u  = (const float*)d_in[0];
  const float* du = (const float*)d_in[1];
  const float* W  = (const float*)d_in[2];
  const float* Bw = (const float*)d_in[3];
  const float* Cw = (const float*)d_in[4];
  const float* h  = (const float*)d_in[5];
  float* y = (float*)d_out;

  char* w = (char*)d_ws;
  size_t off = 0;
  short* z   = (short*)(w + off); off += (size_t)B_SZ * K_CAT * sizeof(short);   // 1.5 MB
  short* Bwb = (short*)(w + off); off += (size_t)H_DIM * K_CAT * sizeof(short);  // 6 MB
  short* Cwb = (short*)(w + off); off += (size_t)Y_DIM * H_DIM * sizeof(short);  // 4 MB
  short* bb  = (short*)(w + off); off += (size_t)B_SZ * H_DIM * sizeof(short);   // 2 MB
  float* wh  = (float*)(w + off); off += H_DIM * sizeof(float);
  float* wth = (float*)(w + off); off += H_DIM * sizeof(float);
  float* yrec= (float*)(w + off); off += Y_DIM * sizeof(float);
  if (ws_size < off) return;

  hipMemsetAsync(wth, 0, H_DIM * sizeof(float), stream);  // wth accumulated via atomics
  k1<<<1280, 256, 0, stream>>>(W, h, du, u, Bw, Cw, wh, wth, z, Bwb, Cwb);
  k2<<<768, 256, 0, stream>>>(z, Bwb, bb, Cw, h, wh, wth, yrec);
  k3<<<256, 256, 0, stream>>>(bb, Cwb, yrec, y);
}

// Round 7
// 123.097 us; speedup vs baseline: 6.2122x; 1.0025x over previous
//
#include <hip/hip_runtime.h>
#include <hip/hip_bf16.h>

// Established: inputs f32, output f32. Threshold 0.038; r3-r6 absmax 0.0078 (1 bf16 ulp).
// Math: y = (rec + DELTA*(cat(du,u)@Bw^T)) @ Cw^T,  rec = h + 0.005*(W@h - W^T@h)
// (expm/inv series truncated at X^1; X^2+ terms contribute <4e-5 -> dropped, r3-r6).
// Harness floor ~58us/iter (268MB ws poison + input restore) -- optimize the rest.
// r7: rec folded into k2 epilogue (bb = bf16(rec + delta*b)); wth via partials (no atomics).

#define B_SZ 512
#define U_DIM 1024
#define DU_DIM 512
#define H_DIM 2048
#define Y_DIM 1024
#define K_CAT 1536
#define DELTA_F 0.01f

typedef __hip_bfloat16 bf16;
using bf16x8f = __attribute__((ext_vector_type(8))) short;
using f32x4   = __attribute__((ext_vector_type(4))) float;

__device__ __forceinline__ short f2bs(float x) {
  union { bf16 b; short s; } u; u.b = __float2bfloat16(x); return u.s;
}
__device__ __forceinline__ int4 pack8(const float4 v0, const float4 v1) {
  union { short s[8]; int4 i; } o;
  o.s[0] = f2bs(v0.x); o.s[1] = f2bs(v0.y); o.s[2] = f2bs(v0.z); o.s[3] = f2bs(v0.w);
  o.s[4] = f2bs(v1.x); o.s[5] = f2bs(v1.y); o.s[6] = f2bs(v1.z); o.s[7] = f2bs(v1.w);
  return o.i;
}

// ---------------- shared MFMA GEMM tile: C[32 x 64] = A[32xK] @ B[64xK]^T -----------
// 256 threads = 4 waves in 2x2; wave computes 16 rows x 32 cols. BK=64, LDS dbuf +
// register prefetch (structure verified r4-r6). LDP=72 shorts (144B stride -> 2-way
// LDS banking, free per m136).
// EPI=0: bb = bf16(rec[col] + DELTA*acc), rec computed from h/wh/wth_part in LDS.
// EPI=1: plain f32 store of acc.
#define LDP 72
#define LDS_SHORTS (2 * 32 * LDP + 2 * 64 * LDP)

template <int KDIM, int EPI>
__device__ __forceinline__ void gemm_tile(short* lds, const short* __restrict__ A,
                                          const short* __restrict__ B,
                                          const float* __restrict__ h, const float* __restrict__ wh,
                                          const float* __restrict__ wtp,
                                          void* __restrict__ out, int Ncols, int mt, int nt) {
  __shared__ float recf[64];
  short* As0 = lds;                   // [2][32*LDP]
  short* Bs0 = lds + 2 * 32 * LDP;    // [2][64*LDP]
  const int tid = threadIdx.x;
  const int lane = tid & 63, wave = tid >> 6;
  const int wm = wave >> 1, wn = wave & 1;
  const int row0 = mt * 32, col0 = nt * 64;
  const int rA = tid >> 3, kc = (tid & 7) * 8;  // A granule row 0..31; B rows rA, rA+32
  f32x4 acc[2] = {};
  int4 pa, pb1, pb2;
  auto ldA  = [&](int kt) { return *(const int4*)(A + (size_t)(row0 + rA) * KDIM + kt * 64 + kc); };
  auto ldB1 = [&](int kt) { return *(const int4*)(B + (size_t)(col0 + rA) * KDIM + kt * 64 + kc); };
  auto ldB2 = [&](int kt) { return *(const int4*)(B + (size_t)(col0 + rA + 32) * KDIM + kt * 64 + kc); };
  pa = ldA(0); pb1 = ldB1(0); pb2 = ldB2(0);
  *(int4*)&As0[rA * LDP + kc] = pa;
  *(int4*)&Bs0[rA * LDP + kc] = pb1;
  *(int4*)&Bs0[(rA + 32) * LDP + kc] = pb2;
  const int NT = KDIM / 64;
  const int kq = (lane >> 4) * 8, rm = lane & 15;
  for (int kt = 0; kt < NT; kt++) {
    const int cur = kt & 1;
    if (kt + 1 < NT) { pa = ldA(kt + 1); pb1 = ldB1(kt + 1); pb2 = ldB2(kt + 1); }
    __syncthreads();
    const short* Ac = As0 + cur * (32 * LDP);
    const short* Bc = Bs0 + cur * (64 * LDP);
    bf16x8f af[2], bfr[2][2];
#pragma unroll
    for (int ks = 0; ks < 2; ks++) {
      af[ks] = *(const bf16x8f*)&Ac[(wm * 16 + rm) * LDP + ks * 32 + kq];
#pragma unroll
      for (int j = 0; j < 2; j++)
        bfr[ks][j] = *(const bf16x8f*)&Bc[(wn * 32 + 16 * j + rm) * LDP + ks * 32 + kq];
    }
#pragma unroll
    for (int ks = 0; ks < 2; ks++)
#pragma unroll
      for (int j = 0; j < 2; j++)
        acc[j] = __builtin_amdgcn_mfma_f32_16x16x32_bf16(af[ks], bfr[ks][j], acc[j], 0, 0, 0);
    if (kt + 1 < NT) {
      short* An = As0 + (cur ^ 1) * (32 * LDP);
      short* Bn = Bs0 + (cur ^ 1) * (64 * LDP);
      *(int4*)&An[rA * LDP + kc] = pa;
      *(int4*)&Bn[rA * LDP + kc] = pb1;
      *(int4*)&Bn[(rA + 32) * LDP + kc] = pb2;
      __syncthreads();
    }
  }
  if (EPI == 0) {  // rec[c] = h[c] + 0.005*(wh[c] - sum_p wth_part[p][c]) for this block's 64 cols
    if (tid < 64) {
      int gc = col0 + tid;
      float s = 0.f;
#pragma unroll
      for (int p = 0; p < 32; p++) s += wtp[p * H_DIM + gc];
      recf[tid] = h[gc] + 0.005f * (wh[gc] - s);
    }
    __syncthreads();
  }
  // C/D: col = lane&15, row = (lane>>4)*4 + reg  [verified r4-r6]
  const int quad = lane >> 4;
#pragma unroll
  for (int j = 0; j < 2; j++) {
    int gc = col0 + wn * 32 + 16 * j + rm;
#pragma unroll
    for (int r = 0; r < 4; r++) {
      int gr = row0 + wm * 16 + quad * 4 + r;
      float v = acc[j][r];
      if (EPI == 0) ((short*)out)[(size_t)gr * Ncols + gc] = f2bs(recf[gc - col0] + DELTA_F * v);
      else          ((float*)out)[(size_t)gr * Ncols + gc] = v;
    }
  }
}

// ---------------- K1: wh = W@h (blk 0..511); wth partials (512..767);  ----------------
// ----------------     convert z|Bw|Cw -> bf16 (768..1279, grid-stride)  ----------------
#define NZ (B_SZ * K_CAT / 8)
#define NB (H_DIM * K_CAT / 8)
#define NC (Y_DIM * H_DIM / 8)

__global__ __launch_bounds__(256) void k1(const float* __restrict__ W, const float* __restrict__ h,
                                          const float* __restrict__ du, const float* __restrict__ u,
                                          const float* __restrict__ Bw, const float* __restrict__ Cw,
                                          float* __restrict__ wh, float* __restrict__ wtp,
                                          short* __restrict__ z, short* __restrict__ Bwb,
                                          short* __restrict__ Cwb) {
  const int b = blockIdx.x;
  if (b < 512) {  // wh[row] = dot(W[row,:], h)
    const int lane = threadIdx.x & 63, wave = threadIdx.x >> 6;
    const int row = b * 4 + wave;
    const float* wr = W + (size_t)row * H_DIM;
    float s = 0.f;
#pragma unroll
    for (int it = 0; it < 8; it++) {
      int k = it * 256 + lane * 4;
      float4 a = *(const float4*)(wr + k);
      float4 hv = *(const float4*)(h + k);
      s += a.x * hv.x + a.y * hv.y + a.z * hv.z + a.w * hv.w;
    }
#pragma unroll
    for (int off = 32; off > 0; off >>= 1) s += __shfl_down(s, off);
    if (lane == 0) wh[row] = s;
  } else if (b < 768) {  // wth partial: wtp[rowg][k] = sum_{i in 64-row chunk} W[i][k]*h[i]
    const int e = b - 512;
    const int colg = e & 7, rowg = e >> 3;
    const int k = colg * 256 + threadIdx.x;
    float s = 0.f;
    const float* base = W + (size_t)rowg * 64 * H_DIM + k;
#pragma unroll 8
    for (int i = 0; i < 64; i++) s += base[(size_t)i * H_DIM] * h[rowg * 64 + i];
    wtp[rowg * H_DIM + k] = s;
  } else {  // bf16 conversions
    const int NG = NZ + NB + NC;
    for (int g = (b - 768) * 256 + threadIdx.x; g < NG; g += 512 * 256) {
      const float* src; short* dst;
      if (g < NZ) {
        int e = g * 8, row = e / K_CAT, col = e % K_CAT;
        src = (col < DU_DIM) ? du + (size_t)row * DU_DIM + col
                             : u + (size_t)row * U_DIM + (col - DU_DIM);
        dst = z + e;
      } else if (g < NZ + NB) {
        int e = (g - NZ) * 8; src = Bw + e; dst = Bwb + e;
      } else {
        int e = (g - NZ - NB) * 8; src = Cw + e; dst = Cwb + e;
      }
      *(int4*)dst = pack8(*(const float4*)src, *(const float4*)(src + 4));
    }
  }
}

// ---------------- K2: bb = bf16(rec[col] + DELTA*(z @ Bwb^T)), 512 tiles ----------------
__global__ __launch_bounds__(256) void k2(const short* __restrict__ z, const short* __restrict__ Bwb,
                                          const float* __restrict__ h, const float* __restrict__ wh,
                                          const float* __restrict__ wtp, short* __restrict__ bb) {
  __shared__ __align__(16) short lds[LDS_SHORTS];
  gemm_tile<K_CAT, 0>(lds, z, Bwb, h, wh, wtp, bb, H_DIM, blockIdx.x >> 5, blockIdx.x & 31);
}

// ---------------- K3: y = bb @ Cwb^T (f32 out), 256 tiles ----------------
__global__ __launch_bounds__(256) void k3(const short* __restrict__ bb, const short* __restrict__ Cwb,
                                          float* __restrict__ y) {
  __shared__ __align__(16) short lds[LDS_SHORTS];
  gemm_tile<H_DIM, 1>(lds, bb, Cwb, nullptr, nullptr, nullptr, y, Y_DIM, blockIdx.x >> 4, blockIdx.x & 15);
}

extern "C" void kernel_launch(void* const* d_in, const int* in_sizes, int n_in,
                              void* d_out, int out_size, void* d_ws, size_t ws_size,
                              hipStream_t stream) {
  const float* u  = (const float*)d_in[0];
  const float* du = (const float*)d_in[1];
  const float* W  = (const float*)d_in[2];
  const float* Bw = (const float*)d_in[3];
  const float* Cw = (const float*)d_in[4];
  const float* h  = (const float*)d_in[5];
  float* y = (float*)d_out;

  char* w = (char*)d_ws;
  size_t off = 0;
  short* z   = (short*)(w + off); off += (size_t)B_SZ * K_CAT * sizeof(short);   // 1.5 MB
  short* Bwb = (short*)(w + off); off += (size_t)H_DIM * K_CAT * sizeof(short);  // 6 MB
  short* Cwb = (short*)(w + off); off += (size_t)Y_DIM * H_DIM * sizeof(short);  // 4 MB
  short* bb  = (short*)(w + off); off += (size_t)B_SZ * H_DIM * sizeof(short);   // 2 MB
  float* wh  = (float*)(w + off); off += H_DIM * sizeof(float);
  float* wtp = (float*)(w + off); off += 32 * H_DIM * sizeof(float);             // 256 KB
  if (ws_size < off) return;

  k1<<<1280, 256, 0, stream>>>(W, h, du, u, Bw, Cw, wh, wtp, z, Bwb, Cwb);
  k2<<<512, 256, 0, stream>>>(z, Bwb, h, wh, wtp, bb);
  k3<<<256, 256, 0, stream>>>(bb, Cwb, y);
}